// Round 6
// baseline (434.464 us; speedup 1.0000x reference)
//
#include <hip/hip_runtime.h>
#include <stdint.h>

// key space: packed key = b<<26 | z<<20 | y<<10 | x  (b<4, z<41, y,x<1024) -> 28 bits.
// Monotone-equivalent to the reference hash b*1025^3+z*1025^2+y*1025+x (bijective).
#define LOGB 28
#define NWORDS (1u << (LOGB - 6))   // 4,194,304 u64 words = 32 MiB bitmap
#define GW 4096                     // words per group (one 256-thread block, 16 words/thread)
#define NGROUPS (NWORDS / GW)       // 1024 groups

typedef unsigned long long u64;

__device__ __forceinline__ uint32_t pack4(int4 v) {
    return ((uint32_t)v.x << 26) | ((uint32_t)v.y << 20) | ((uint32_t)v.z << 10) | (uint32_t)v.w;
}

// ---------------- block scan helper (blockDim == 256) ----------------
__device__ __forceinline__ uint32_t block_incl_scan_256(uint32_t v, uint32_t* s) {
    int t = threadIdx.x;
    s[t] = v;
    __syncthreads();
    #pragma unroll
    for (int off = 1; off < 256; off <<= 1) {
        uint32_t u = (t >= off) ? s[t - off] : 0u;
        __syncthreads();
        s[t] += u;
        __syncthreads();
    }
    return s[t];
}

// ---------------- phase 1: presence bitmap ----------------
// students are unique coords (subset of teacher uniques); count new bits per group.
__global__ void set_bits(const int* __restrict__ sidx, u64* __restrict__ bitmap,
                         uint32_t* __restrict__ groupSum, int ns) {
    int i = blockIdx.x * blockDim.x + threadIdx.x;
    if (i >= ns) return;
    uint32_t k = pack4(((const int4*)sidx)[i]);
    u64 bit = 1ull << (k & 63u);
    u64 old = atomicOr(&bitmap[k >> 6], bit);
    if (!(old & bit)) atomicAdd(&groupSum[k >> (6 + 12)], 1u);   // k>>6 / GW, GW=2^12
}

// single block: exclusive scan of NGROUPS group sums
__global__ void scan_groups(uint32_t* __restrict__ groupSum, int n) {
    __shared__ uint32_t s[256];
    uint32_t run = 0;
    for (int c = 0; c < n; c += 256) {
        int i = c + (int)threadIdx.x;
        uint32_t v = (i < n) ? groupSum[i] : 0u;
        uint32_t incl = block_incl_scan_256(v, s);
        if (i < n) groupSum[i] = incl - v + run;
        run += s[255];
        __syncthreads();
    }
}

// ---------------- phase 2: per-word rank + sorted indice output ----------------
// For each set bit (in ascending key order) rank r is its sorted position:
// write wordPrefix[w] (for teacher probes) and decode key -> outI[r].
__global__ void word_prefix_indice(const u64* __restrict__ bitmap,
                                   const uint32_t* __restrict__ groupBase,
                                   uint32_t* __restrict__ wordPrefix,
                                   float* __restrict__ outI) {
    __shared__ uint32_t s[256];
    size_t w0 = (size_t)blockIdx.x * GW + (size_t)threadIdx.x * 16;
    uint32_t tsum = 0;
    #pragma unroll
    for (int j = 0; j < 16; ++j) tsum += (uint32_t)__popcll(bitmap[w0 + j]);
    uint32_t incl = block_incl_scan_256(tsum, s);
    uint32_t run = groupBase[blockIdx.x] + incl - tsum;   // exclusive rank at this thread's first word
    #pragma unroll
    for (int j = 0; j < 16; ++j) {
        u64 word = bitmap[w0 + j];
        wordPrefix[w0 + j] = run;
        while (word) {
            int b = (int)__builtin_ctzll(word);
            word &= word - 1;
            uint32_t k = ((uint32_t)(w0 + j) << 6) | (uint32_t)b;
            ((float4*)outI)[run++] = make_float4(
                (float)(k >> 26), (float)((k >> 20) & 63u),
                (float)((k >> 10) & 1023u), (float)(k & 1023u));
        }
    }
}

// ---------------- phase 3: teacher probe (2 independent loads, no chain) ----------------
__global__ void teacher_probe(const int* __restrict__ tidx, const u64* __restrict__ bitmap,
                              const uint32_t* __restrict__ wordPrefix,
                              uint32_t* __restrict__ cnt, int* __restrict__ pos, int nt) {
    int t = blockIdx.x * blockDim.x + threadIdx.x;
    if (t >= nt) return;
    uint32_t k = pack4(((const int4*)tidx)[t]);
    u64 word = bitmap[k >> 6];
    u64 bit  = 1ull << (k & 63u);
    if (word & bit) {
        int p = (int)(wordPrefix[k >> 6] + (uint32_t)__popcll(word & (bit - 1ull)));
        pos[t] = p;
        atomicAdd(&cnt[p], 1u);
    } else {
        pos[t] = -1;
    }
}

// zero only the rare multi-contributor rows (cnt>1); cnt==1 rows are fully
// overwritten by plain stores in the write pass (every student pos has cnt>=1).
__global__ void zero_multi(const uint32_t* __restrict__ cnt, float* __restrict__ feat, int ns) {
    int s = blockIdx.x * blockDim.x + threadIdx.x;
    if (s >= ns) return;
    if (cnt[s] > 1u) {
        float4* d4 = (float4*)(feat + (size_t)s * 32);
        #pragma unroll
        for (int q = 0; q < 8; ++q) d4[q] = make_float4(0.f, 0.f, 0.f, 0.f);
    }
}

// ---------------- phase 4: feature write (no search; pos precomputed) ----------------
__global__ void teacher_write(const float* __restrict__ tfeat, const int* __restrict__ pos,
                              const uint32_t* __restrict__ cnt, float* __restrict__ feat, int nt) {
    int t = blockIdx.x * blockDim.x + threadIdx.x;
    if (t >= nt) return;
    int p = pos[t];
    if (p < 0) return;
    const float4* src = (const float4*)(tfeat + (size_t)t * 32);
    float* dst = feat + (size_t)p * 32;
    if (cnt[p] == 1u) {
        float4* d4 = (float4*)dst;
        #pragma unroll
        for (int q = 0; q < 8; ++q) d4[q] = src[q];
    } else {
        #pragma unroll
        for (int q = 0; q < 8; ++q) {
            float4 f = src[q];
            atomicAdd(dst + q * 4 + 0, f.x);
            atomicAdd(dst + q * 4 + 1, f.y);
            atomicAdd(dst + q * 4 + 2, f.z);
            atomicAdd(dst + q * 4 + 3, f.w);
        }
    }
}

extern "C" void kernel_launch(void* const* d_in, const int* in_sizes, int n_in,
                              void* d_out, int out_size, void* d_ws, size_t ws_size,
                              hipStream_t stream) {
    const float* tfeat = (const float*)d_in[0];
    const int*   tidx  = (const int*)d_in[1];
    const int*   sidx  = (const int*)d_in[2];

    const int NT = in_sizes[1] / 4;
    const int NS = in_sizes[2] / 4;

    float* feat = (float*)d_out;                        // [NS, 32]
    float* outI = (float*)d_out + (size_t)NS * 32;      // [NS, 4] as floats

    // workspace layout (bytes). ws_size ~1 GB (rocprof: 1.024e9 B poison fill) >> 62 MB needed.
    // [bitmap 32MiB][cnt NS*4][groupSum NGROUPS*4]  <- one contiguous zero-fill
    // [wordPrefix 16MiB][pos NT*4]
    char* base = (char*)d_ws;
    u64*      bitmap     = (u64*)base;
    uint32_t* cnt        = (uint32_t*)(base + (size_t)NWORDS * 8);
    uint32_t* groupSum   = cnt + NS;
    size_t    zeroBytes  = (size_t)NWORDS * 8 + (size_t)NS * 4 + (size_t)NGROUPS * 4;
    uint32_t* wordPrefix = groupSum + NGROUPS;
    int*      pos        = (int*)(wordPrefix + NWORDS);

    hipMemsetAsync(d_ws, 0, zeroBytes, stream);

    set_bits<<<(NS + 255) / 256, 256, 0, stream>>>(sidx, bitmap, groupSum, NS);
    scan_groups<<<1, 256, 0, stream>>>(groupSum, NGROUPS);
    word_prefix_indice<<<NGROUPS, 256, 0, stream>>>(bitmap, groupSum, wordPrefix, outI);
    teacher_probe<<<(NT + 255) / 256, 256, 0, stream>>>(tidx, bitmap, wordPrefix, cnt, pos, NT);
    zero_multi<<<(NS + 255) / 256, 256, 0, stream>>>(cnt, feat, NS);
    teacher_write<<<(NT + 255) / 256, 256, 0, stream>>>(tfeat, pos, cnt, feat, NT);
}

// Round 7
// 234.572 us; speedup vs baseline: 1.8522x; 1.8522x over previous
//
#include <hip/hip_runtime.h>
#include <stdint.h>

// key space: packed key = b<<26 | z<<20 | y<<10 | x  (b<4, z<41, y,x<1024) -> 28 bits.
// Monotone-equivalent to the reference hash b*1025^3+z*1025^2+y*1025+x (bijective).
#define LOGB 28
#define NWORDS (1u << (LOGB - 6))   // 4,194,304 u64 words = 32 MiB bitmap
#define GW 4096                     // words per group (one 256-thread block, 16 words/thread)
#define NGROUPS (NWORDS / GW)       // 1024 groups

typedef unsigned long long u64;

__device__ __forceinline__ uint32_t pack4(int4 v) {
    return ((uint32_t)v.x << 26) | ((uint32_t)v.y << 20) | ((uint32_t)v.z << 10) | (uint32_t)v.w;
}

// ---------------- block scan helper (blockDim == 256) ----------------
__device__ __forceinline__ uint32_t block_incl_scan_256(uint32_t v, uint32_t* s) {
    int t = threadIdx.x;
    s[t] = v;
    __syncthreads();
    #pragma unroll
    for (int off = 1; off < 256; off <<= 1) {
        uint32_t u = (t >= off) ? s[t - off] : 0u;
        __syncthreads();
        s[t] += u;
        __syncthreads();
    }
    return s[t];
}

// ---------------- phase 1: presence bitmap ----------------
// Fire-and-forget atomicOr only — no return value, no contended counter.
// (Round-6 lesson: 800K atomicAdd onto ~41 cache lines serialized at ~12ns each = 240us.)
__global__ void set_bits(const int* __restrict__ sidx, u64* __restrict__ bitmap, int ns) {
    int i = blockIdx.x * blockDim.x + threadIdx.x;
    if (i >= ns) return;
    uint32_t k = pack4(((const int4*)sidx)[i]);
    atomicOr(&bitmap[k >> 6], 1ull << (k & 63u));
}

// ---------------- phase 1.5: per-group bit counts via streaming popcount ----------------
__global__ void group_popcount(const u64* __restrict__ bitmap, uint32_t* __restrict__ groupSum) {
    __shared__ uint32_t s[256];
    size_t w0 = (size_t)blockIdx.x * GW + (size_t)threadIdx.x * 16;
    uint32_t t = 0;
    #pragma unroll
    for (int j = 0; j < 16; ++j) t += (uint32_t)__popcll(bitmap[w0 + j]);
    s[threadIdx.x] = t;
    __syncthreads();
    #pragma unroll
    for (int off = 128; off > 0; off >>= 1) {
        if (threadIdx.x < (unsigned)off) s[threadIdx.x] += s[threadIdx.x + off];
        __syncthreads();
    }
    if (threadIdx.x == 0) groupSum[blockIdx.x] = s[0];
}

// single block: exclusive scan of NGROUPS group sums
__global__ void scan_groups(uint32_t* __restrict__ groupSum, int n) {
    __shared__ uint32_t s[256];
    uint32_t run = 0;
    for (int c = 0; c < n; c += 256) {
        int i = c + (int)threadIdx.x;
        uint32_t v = (i < n) ? groupSum[i] : 0u;
        uint32_t incl = block_incl_scan_256(v, s);
        if (i < n) groupSum[i] = incl - v + run;
        run += s[255];
        __syncthreads();
    }
}

// ---------------- phase 2: per-word rank + sorted indice output ----------------
// For each set bit (in ascending key order) rank r is its sorted position:
// write wordPrefix[w] (for teacher probes) and decode key -> outI[r].
__global__ void word_prefix_indice(const u64* __restrict__ bitmap,
                                   const uint32_t* __restrict__ groupBase,
                                   uint32_t* __restrict__ wordPrefix,
                                   float* __restrict__ outI) {
    __shared__ uint32_t s[256];
    size_t w0 = (size_t)blockIdx.x * GW + (size_t)threadIdx.x * 16;
    uint32_t tsum = 0;
    #pragma unroll
    for (int j = 0; j < 16; ++j) tsum += (uint32_t)__popcll(bitmap[w0 + j]);
    uint32_t incl = block_incl_scan_256(tsum, s);
    uint32_t run = groupBase[blockIdx.x] + incl - tsum;   // exclusive rank at this thread's first word
    #pragma unroll
    for (int j = 0; j < 16; ++j) {
        u64 word = bitmap[w0 + j];
        wordPrefix[w0 + j] = run;
        while (word) {
            int b = (int)__builtin_ctzll(word);
            word &= word - 1;
            uint32_t k = ((uint32_t)(w0 + j) << 6) | (uint32_t)b;
            ((float4*)outI)[run++] = make_float4(
                (float)(k >> 26), (float)((k >> 20) & 63u),
                (float)((k >> 10) & 1023u), (float)(k & 1023u));
        }
    }
}

// ---------------- phase 3: teacher probe (2 independent loads, no chain) ----------------
__global__ void teacher_probe(const int* __restrict__ tidx, const u64* __restrict__ bitmap,
                              const uint32_t* __restrict__ wordPrefix,
                              uint32_t* __restrict__ cnt, int* __restrict__ pos, int nt) {
    int t = blockIdx.x * blockDim.x + threadIdx.x;
    if (t >= nt) return;
    uint32_t k = pack4(((const int4*)tidx)[t]);
    u64 word = bitmap[k >> 6];
    u64 bit  = 1ull << (k & 63u);
    if (word & bit) {
        int p = (int)(wordPrefix[k >> 6] + (uint32_t)__popcll(word & (bit - 1ull)));
        pos[t] = p;
        atomicAdd(&cnt[p], 1u);   // 2M atomics over 50K lines -> ~40/line, negligible serialization
    } else {
        pos[t] = -1;
    }
}

// zero only the rare multi-contributor rows (cnt>1); cnt==1 rows are fully
// overwritten by plain stores in the write pass (every student pos has cnt>=1).
__global__ void zero_multi(const uint32_t* __restrict__ cnt, float* __restrict__ feat, int ns) {
    int s = blockIdx.x * blockDim.x + threadIdx.x;
    if (s >= ns) return;
    if (cnt[s] > 1u) {
        float4* d4 = (float4*)(feat + (size_t)s * 32);
        #pragma unroll
        for (int q = 0; q < 8; ++q) d4[q] = make_float4(0.f, 0.f, 0.f, 0.f);
    }
}

// ---------------- phase 4: feature write (no search; pos precomputed) ----------------
__global__ void teacher_write(const float* __restrict__ tfeat, const int* __restrict__ pos,
                              const uint32_t* __restrict__ cnt, float* __restrict__ feat, int nt) {
    int t = blockIdx.x * blockDim.x + threadIdx.x;
    if (t >= nt) return;
    int p = pos[t];
    if (p < 0) return;
    const float4* src = (const float4*)(tfeat + (size_t)t * 32);
    float* dst = feat + (size_t)p * 32;
    if (cnt[p] == 1u) {
        float4* d4 = (float4*)dst;
        #pragma unroll
        for (int q = 0; q < 8; ++q) d4[q] = src[q];
    } else {
        #pragma unroll
        for (int q = 0; q < 8; ++q) {
            float4 f = src[q];
            atomicAdd(dst + q * 4 + 0, f.x);
            atomicAdd(dst + q * 4 + 1, f.y);
            atomicAdd(dst + q * 4 + 2, f.z);
            atomicAdd(dst + q * 4 + 3, f.w);
        }
    }
}

extern "C" void kernel_launch(void* const* d_in, const int* in_sizes, int n_in,
                              void* d_out, int out_size, void* d_ws, size_t ws_size,
                              hipStream_t stream) {
    const float* tfeat = (const float*)d_in[0];
    const int*   tidx  = (const int*)d_in[1];
    const int*   sidx  = (const int*)d_in[2];

    const int NT = in_sizes[1] / 4;
    const int NS = in_sizes[2] / 4;

    float* feat = (float*)d_out;                        // [NS, 32]
    float* outI = (float*)d_out + (size_t)NS * 32;      // [NS, 4] as floats

    // workspace layout (bytes). ws_size ~1 GB >> ~68 MB needed.
    // [bitmap 32MiB][cnt NS*4]  <- one contiguous zero-fill
    // [groupSum NGROUPS*4][wordPrefix 16MiB][pos NT*4]
    char* base = (char*)d_ws;
    u64*      bitmap     = (u64*)base;
    uint32_t* cnt        = (uint32_t*)(base + (size_t)NWORDS * 8);
    size_t    zeroBytes  = (size_t)NWORDS * 8 + (size_t)NS * 4;
    uint32_t* groupSum   = cnt + NS;
    uint32_t* wordPrefix = groupSum + NGROUPS;
    int*      pos        = (int*)(wordPrefix + NWORDS);

    hipMemsetAsync(d_ws, 0, zeroBytes, stream);

    set_bits<<<(NS + 255) / 256, 256, 0, stream>>>(sidx, bitmap, NS);
    group_popcount<<<NGROUPS, 256, 0, stream>>>(bitmap, groupSum);
    scan_groups<<<1, 256, 0, stream>>>(groupSum, NGROUPS);
    word_prefix_indice<<<NGROUPS, 256, 0, stream>>>(bitmap, groupSum, wordPrefix, outI);
    teacher_probe<<<(NT + 255) / 256, 256, 0, stream>>>(tidx, bitmap, wordPrefix, cnt, pos, NT);
    zero_multi<<<(NS + 255) / 256, 256, 0, stream>>>(cnt, feat, NS);
    teacher_write<<<(NT + 255) / 256, 256, 0, stream>>>(tfeat, pos, cnt, feat, NT);
}